// Round 1
// baseline (1736.281 us; speedup 1.0000x reference)
//
#include <hip/hip_runtime.h>
#include <hip/hip_bf16.h>

// ---------------------------------------------------------------------------
// CondGCN: heterogeneous graph conv.
// Key optimization vs reference: messages depend only on src node -> compute
// relu(W·feat+b) per NODE (not per edge), then edges just gather+scatter-add.
// ---------------------------------------------------------------------------

// Generic per-node transform: out[n][64] = (relu?)(in[n][F] @ W^T + b)
// One wave per node. Lane d owns W row d in VGPRs (loaded once), input row is
// wave-uniform (same-address broadcast float4 loads), output coalesced.
template <int F, bool RELU>
__global__ __launch_bounds__(256) void transform_kernel(
    const float* __restrict__ in, const float* __restrict__ W,
    const float* __restrict__ b, float* __restrict__ out, int n)
{
    const int lane  = threadIdx.x & 63;
    const int wid   = (int)((blockIdx.x * (unsigned)blockDim.x + threadIdx.x) >> 6);
    const int nwav  = (int)((gridDim.x * (unsigned)blockDim.x) >> 6);

    // Load this lane's W row (64 output dims == 64 lanes).
    float w[F];
    const float4* wrow = reinterpret_cast<const float4*>(W + (size_t)lane * F);
#pragma unroll
    for (int k4 = 0; k4 < F / 4; ++k4) {
        float4 v = wrow[k4];
        w[4 * k4 + 0] = v.x; w[4 * k4 + 1] = v.y;
        w[4 * k4 + 2] = v.z; w[4 * k4 + 3] = v.w;
    }
    const float bias = b[lane];

    for (int node = wid; node < n; node += nwav) {
        const float4* xr = reinterpret_cast<const float4*>(in + (size_t)node * F);
        float acc = bias;
#pragma unroll
        for (int k4 = 0; k4 < F / 4; ++k4) {
            float4 v = xr[k4];  // wave-uniform address -> broadcast
            acc += v.x * w[4 * k4 + 0];
            acc += v.y * w[4 * k4 + 1];
            acc += v.z * w[4 * k4 + 2];
            acc += v.w * w[4 * k4 + 3];
        }
        if (RELU) acc = fmaxf(acc, 0.0f);
        out[(size_t)node * 64 + lane] = acc;
    }
}

// Edge scatter-add: wave per edge, lane d handles feature dim d.
// agg[dst][d] += h[src][d]   (h = precomputed per-node messages)
__global__ __launch_bounds__(256) void scatter_kernel(
    const int* __restrict__ src, const int* __restrict__ dst,
    const float* __restrict__ h, float* __restrict__ agg, int E)
{
    const int d    = threadIdx.x & 63;
    const int wid  = (int)((blockIdx.x * (unsigned)blockDim.x + threadIdx.x) >> 6);
    const int nwav = (int)((gridDim.x * (unsigned)blockDim.x) >> 6);

    for (int e = wid; e < E; e += nwav) {
        const int s = src[e];   // wave-uniform
        const int t = dst[e];   // wave-uniform
        float v = h[(size_t)s * 64 + d];          // coalesced 256B row gather
        unsafeAtomicAdd(&agg[(size_t)t * 64 + d], v);  // HW global_atomic_add_f32
    }
}

extern "C" void kernel_launch(void* const* d_in, const int* in_sizes, int n_in,
                              void* d_out, int out_size, void* d_ws, size_t ws_size,
                              hipStream_t stream)
{
    const float* x = (const float*)d_in[0];
    const float* c = (const float*)d_in[1];
    const float* r = (const float*)d_in[2];
    const int* exx_s = (const int*)d_in[3];
    const int* exx_d = (const int*)d_in[4];
    const int* ecx_s = (const int*)d_in[5];
    const int* ecx_d = (const int*)d_in[6];
    const int* erx_s = (const int*)d_in[7];
    const int* erx_d = (const int*)d_in[8];
    const float* W_x  = (const float*)d_in[9];
    const float* b_x  = (const float*)d_in[10];
    const float* W_c  = (const float*)d_in[11];
    const float* b_c  = (const float*)d_in[12];
    const float* W_r  = (const float*)d_in[13];
    const float* b_r  = (const float*)d_in[14];
    const float* W_xx = (const float*)d_in[15];
    const float* b_xx = (const float*)d_in[16];
    const float* W_cx = (const float*)d_in[17];
    const float* b_cx = (const float*)d_in[18];
    const float* W_rx = (const float*)d_in[19];
    const float* b_rx = (const float*)d_in[20];
    const float* W_pool = (const float*)d_in[21];
    const float* b_pool = (const float*)d_in[22];

    const int N_x = in_sizes[0] / 64;
    const int N_c = in_sizes[1] / 32;
    const int N_r = in_sizes[2] / 48;
    const int E_xx = in_sizes[3];
    const int E_cx = in_sizes[5];
    const int E_rx = in_sizes[7];

    float* ws = (float*)d_ws;
    float* agg  = ws;                              // [N_x][64]
    float* h_xx = agg  + (size_t)N_x * 64;         // [N_x][64]
    float* h_cx = h_xx + (size_t)N_x * 64;         // [N_c][64]
    float* h_rx = h_cx + (size_t)N_c * 64;         // [N_r][64]

    float* out_x = (float*)d_out;                  // [N_x][64]
    float* out_c = out_x + (size_t)N_x * 64;       // [N_c][64]
    float* out_r = out_c + (size_t)N_c * 64;       // [N_r][64]

    const int BLK = 256;                           // 4 waves/block
    auto blocks_for_nodes = [](int n) { return (n + 3) / 4; };

    // Per-node transforms. agg is fully overwritten with the self-loop term,
    // so no memset is needed before the scatter-adds.
    transform_kernel<64, true><<<blocks_for_nodes(N_x), BLK, 0, stream>>>(x, W_x,  b_x,  agg,  N_x);
    transform_kernel<64, true><<<blocks_for_nodes(N_x), BLK, 0, stream>>>(x, W_xx, b_xx, h_xx, N_x);
    transform_kernel<32, true><<<blocks_for_nodes(N_c), BLK, 0, stream>>>(c, W_cx, b_cx, h_cx, N_c);
    transform_kernel<48, true><<<blocks_for_nodes(N_r), BLK, 0, stream>>>(r, W_rx, b_rx, h_rx, N_r);
    transform_kernel<32, true><<<blocks_for_nodes(N_c), BLK, 0, stream>>>(c, W_c,  b_c,  out_c, N_c);
    transform_kernel<48, true><<<blocks_for_nodes(N_r), BLK, 0, stream>>>(r, W_r,  b_r,  out_r, N_r);

    // Edge scatter-adds into agg (stream-ordered after agg/h_* are ready).
    const int SBLK = 4096;                         // 16K waves
    scatter_kernel<<<SBLK, BLK, 0, stream>>>(exx_s, exx_d, h_xx, agg, E_xx);
    scatter_kernel<<<SBLK, BLK, 0, stream>>>(ecx_s, ecx_d, h_cx, agg, E_cx);
    scatter_kernel<<<SBLK, BLK, 0, stream>>>(erx_s, erx_d, h_rx, agg, E_rx);

    // Final pool: x_out = agg @ W_pool^T + b_pool  (no relu)
    transform_kernel<64, false><<<blocks_for_nodes(N_x), BLK, 0, stream>>>(agg, W_pool, b_pool, out_x, N_x);
}

// Round 3
// 1104.046 us; speedup vs baseline: 1.5727x; 1.5727x over previous
//
#include <hip/hip_runtime.h>
#include <hip/hip_bf16.h>

// ---------------------------------------------------------------------------
// CondGCN round 2 (resubmit — round-2 bench was an infra timeout):
//  - messages computed per NODE (not per edge)
//  - atomic scatter replaced by combined dst-sorted CSR + register gather
//    (round-1 counters: 512MB atomic write-through, ~300G atomics/s = TCC
//     atomic ALU ceiling; HBM only 24% busy)
//  - transform kernels grid-capped so each wave amortizes its W tile over
//    many nodes (was 1 node/wave -> 1.6GB redundant W traffic per pass)
// ---------------------------------------------------------------------------

// out[n][64] = (relu?)(in[n][F] @ W^T + b). Lane = output dim, wave-uniform
// broadcast loads of the input row, grid-stride over nodes.
template <int F, bool RELU>
__global__ __launch_bounds__(256) void transform_kernel(
    const float* __restrict__ in, const float* __restrict__ W,
    const float* __restrict__ b, float* __restrict__ out, int n)
{
    const int lane  = threadIdx.x & 63;
    const int wid   = (int)((blockIdx.x * (unsigned)blockDim.x + threadIdx.x) >> 6);
    const int nwav  = (int)((gridDim.x * (unsigned)blockDim.x) >> 6);

    float w[F];
    const float4* wrow = reinterpret_cast<const float4*>(W + (size_t)lane * F);
#pragma unroll
    for (int k4 = 0; k4 < F / 4; ++k4) {
        float4 v = wrow[k4];
        w[4 * k4 + 0] = v.x; w[4 * k4 + 1] = v.y;
        w[4 * k4 + 2] = v.z; w[4 * k4 + 3] = v.w;
    }
    const float bias = b[lane];

    for (int node = wid; node < n; node += nwav) {
        const float4* xr = reinterpret_cast<const float4*>(in + (size_t)node * F);
        float acc = bias;
#pragma unroll
        for (int k4 = 0; k4 < F / 4; ++k4) {
            float4 v = xr[k4];
            acc += v.x * w[4 * k4 + 0];
            acc += v.y * w[4 * k4 + 1];
            acc += v.z * w[4 * k4 + 2];
            acc += v.w * w[4 * k4 + 3];
        }
        if (RELU) acc = fmaxf(acc, 0.0f);
        out[(size_t)node * 64 + lane] = acc;
    }
}

// deg[dst[i]] += 1 over one edge list
__global__ __launch_bounds__(256) void hist_kernel(
    const int* __restrict__ dst, int E, int* __restrict__ deg)
{
    int i = blockIdx.x * blockDim.x + threadIdx.x;
    int stride = gridDim.x * blockDim.x;
    for (; i < E; i += stride) atomicAdd(&deg[dst[i]], 1);
}

// Exclusive scan of deg[0..n) -> offsets[0..n]. Single block of 1024 threads.
__global__ __launch_bounds__(1024) void scan_kernel(
    const int* __restrict__ deg, int* __restrict__ offsets, int n)
{
    __shared__ int sums[1024];
    const int t = threadIdx.x;
    const int chunk = (n + 1023) / 1024;
    const int beg = t * chunk;
    const int end = min(n, beg + chunk);
    int s = 0;
    for (int i = beg; i < end; ++i) s += deg[i];
    sums[t] = s;
    __syncthreads();
    // inclusive Hillis-Steele scan over the 1024 partial sums
    for (int off = 1; off < 1024; off <<= 1) {
        int v = (t >= off) ? sums[t - off] : 0;
        __syncthreads();
        sums[t] += v;
        __syncthreads();
    }
    int run = (t == 0) ? 0 : sums[t - 1];
    for (int i = beg; i < end; ++i) { offsets[i] = run; run += deg[i]; }
    if (t == 0) offsets[n] = sums[1023];
}

// rows[offsets[dst]+k] = base + src  (cursor = per-dst running count, pre-zeroed)
__global__ __launch_bounds__(256) void bucket_kernel(
    const int* __restrict__ src, const int* __restrict__ dst, int E,
    const int* __restrict__ offsets, int* __restrict__ cursor,
    int* __restrict__ rows, int base)
{
    int i = blockIdx.x * blockDim.x + threadIdx.x;
    int stride = gridDim.x * blockDim.x;
    for (; i < E; i += stride) {
        int t = dst[i];
        int pos = offsets[t] + atomicAdd(&cursor[t], 1);
        rows[pos] = base + src[i];
    }
}

// agg[node] += sum over in-edges of H[row]. One wave per node, lane = dim.
__global__ __launch_bounds__(256) void gather_kernel(
    const int* __restrict__ offsets, const int* __restrict__ rows,
    const float* __restrict__ H, float* __restrict__ agg, int n)
{
    const int lane  = threadIdx.x & 63;
    const int wid   = (int)((blockIdx.x * (unsigned)blockDim.x + threadIdx.x) >> 6);
    const int nwav  = (int)((gridDim.x * (unsigned)blockDim.x) >> 6);
    const float* Hl = H + lane;

    for (int node = wid; node < n; node += nwav) {
        const int beg = offsets[node];
        const int end = offsets[node + 1];
        float acc = agg[(size_t)node * 64 + lane];
        int o = beg;
        while (o < end) {
            const int m = min(64, end - o);
            int idx = (lane < m) ? rows[o + lane] : 0;   // coalesced index load
#pragma unroll 4
            for (int j = 0; j < m; ++j) {
                int rj = __shfl(idx, j);                  // broadcast
                acc += Hl[(size_t)rj * 64];               // coalesced 256B row
            }
            o += m;
        }
        agg[(size_t)node * 64 + lane] = acc;
    }
}

extern "C" void kernel_launch(void* const* d_in, const int* in_sizes, int n_in,
                              void* d_out, int out_size, void* d_ws, size_t ws_size,
                              hipStream_t stream)
{
    const float* x = (const float*)d_in[0];
    const float* c = (const float*)d_in[1];
    const float* r = (const float*)d_in[2];
    const int* exx_s = (const int*)d_in[3];
    const int* exx_d = (const int*)d_in[4];
    const int* ecx_s = (const int*)d_in[5];
    const int* ecx_d = (const int*)d_in[6];
    const int* erx_s = (const int*)d_in[7];
    const int* erx_d = (const int*)d_in[8];
    const float* W_x  = (const float*)d_in[9];
    const float* b_x  = (const float*)d_in[10];
    const float* W_c  = (const float*)d_in[11];
    const float* b_c  = (const float*)d_in[12];
    const float* W_r  = (const float*)d_in[13];
    const float* b_r  = (const float*)d_in[14];
    const float* W_xx = (const float*)d_in[15];
    const float* b_xx = (const float*)d_in[16];
    const float* W_cx = (const float*)d_in[17];
    const float* b_cx = (const float*)d_in[18];
    const float* W_rx = (const float*)d_in[19];
    const float* b_rx = (const float*)d_in[20];
    const float* W_pool = (const float*)d_in[21];
    const float* b_pool = (const float*)d_in[22];

    const int N_x = in_sizes[0] / 64;
    const int N_c = in_sizes[1] / 32;
    const int N_r = in_sizes[2] / 48;
    const int E_xx = in_sizes[3];
    const int E_cx = in_sizes[5];
    const int E_rx = in_sizes[7];

    // workspace layout
    float* ws   = (float*)d_ws;
    float* agg  = ws;                                   // [N_x][64]
    float* H    = agg + (size_t)N_x * 64;               // [(N_x+N_c+N_r)][64]
    float* h_xx = H;
    float* h_cx = H + (size_t)N_x * 64;
    float* h_rx = H + (size_t)(N_x + N_c) * 64;
    int*   deg     = (int*)(H + (size_t)(N_x + N_c + N_r) * 64);  // [N_x] (also cursor)
    int*   offsets = deg + N_x;                         // [N_x+1]
    int*   rows    = offsets + N_x + 1;                 // [E_xx+E_cx+E_rx]

    float* out_x = (float*)d_out;                       // [N_x][64]
    float* out_c = out_x + (size_t)N_x * 64;            // [N_c][64]
    float* out_r = out_c + (size_t)N_c * 64;            // [N_r][64]

    const int BLK = 256;
    const int TGRID = 2048;   // transform grid: 8192 waves, grid-stride nodes
    const int EGRID = 1024;   // edge-parallel kernels

    // per-node transforms (agg = self-loop term; fully overwritten)
    transform_kernel<64, true><<<TGRID, BLK, 0, stream>>>(x, W_x,  b_x,  agg,  N_x);
    transform_kernel<64, true><<<TGRID, BLK, 0, stream>>>(x, W_xx, b_xx, h_xx, N_x);
    transform_kernel<32, true><<<TGRID, BLK, 0, stream>>>(c, W_cx, b_cx, h_cx, N_c);
    transform_kernel<48, true><<<TGRID, BLK, 0, stream>>>(r, W_rx, b_rx, h_rx, N_r);
    transform_kernel<32, true><<<TGRID, BLK, 0, stream>>>(c, W_c,  b_c,  out_c, N_c);
    transform_kernel<48, true><<<TGRID, BLK, 0, stream>>>(r, W_r,  b_r,  out_r, N_r);

    // combined CSR over all 3 relations (dst space is x-nodes for all)
    hipMemsetAsync(deg, 0, (size_t)N_x * sizeof(int), stream);
    hist_kernel<<<EGRID, BLK, 0, stream>>>(exx_d, E_xx, deg);
    hist_kernel<<<EGRID, BLK, 0, stream>>>(ecx_d, E_cx, deg);
    hist_kernel<<<EGRID, BLK, 0, stream>>>(erx_d, E_rx, deg);
    scan_kernel<<<1, 1024, 0, stream>>>(deg, offsets, N_x);
    hipMemsetAsync(deg, 0, (size_t)N_x * sizeof(int), stream);  // reuse as cursor
    bucket_kernel<<<EGRID, BLK, 0, stream>>>(exx_s, exx_d, E_xx, offsets, deg, rows, 0);
    bucket_kernel<<<EGRID, BLK, 0, stream>>>(ecx_s, ecx_d, E_cx, offsets, deg, rows, N_x);
    bucket_kernel<<<EGRID, BLK, 0, stream>>>(erx_s, erx_d, E_rx, offsets, deg, rows, N_x + N_c);

    // atomic-free accumulate
    gather_kernel<<<TGRID, BLK, 0, stream>>>(offsets, rows, H, agg, N_x);

    // x_out = agg @ W_pool^T + b_pool
    transform_kernel<64, false><<<TGRID, BLK, 0, stream>>>(agg, W_pool, b_pool, out_x, N_x);
}

// Round 5
// 1101.894 us; speedup vs baseline: 1.5757x; 1.0020x over previous
//
#include <hip/hip_runtime.h>
#include <hip/hip_bf16.h>

// ---------------------------------------------------------------------------
// CondGCN round 4 (resubmit — round-4 bench was a broker capacity timeout):
//  - gather: 8-deep load pipeline + 4 accumulator chains (r3 counters: 24.7%
//    HBM, 23.7% VALU, 80% occ -> latency-bound, only ~4 loads in flight)
//  - transforms fused in pairs sharing the input (x,c,r each read ONCE)
//  - CSR build fused: 1 hist + 1 bucket over concatenated edge lists,
//    scan self-clears deg (cursor) -> 9 dispatches total (was 17)
// ---------------------------------------------------------------------------

// Single transform: out[n][64] = (relu?)(in[n][F] @ W^T + b)
template <int F, bool RELU>
__global__ __launch_bounds__(256) void transform_kernel(
    const float* __restrict__ in, const float* __restrict__ W,
    const float* __restrict__ b, float* __restrict__ out, int n)
{
    const int lane  = threadIdx.x & 63;
    const int wid   = (int)((blockIdx.x * (unsigned)blockDim.x + threadIdx.x) >> 6);
    const int nwav  = (int)((gridDim.x * (unsigned)blockDim.x) >> 6);

    float w[F];
    const float4* wrow = reinterpret_cast<const float4*>(W + (size_t)lane * F);
#pragma unroll
    for (int k4 = 0; k4 < F / 4; ++k4) {
        float4 v = wrow[k4];
        w[4 * k4 + 0] = v.x; w[4 * k4 + 1] = v.y;
        w[4 * k4 + 2] = v.z; w[4 * k4 + 3] = v.w;
    }
    const float bias = b[lane];

    for (int node = wid; node < n; node += nwav) {
        const float4* xr = reinterpret_cast<const float4*>(in + (size_t)node * F);
        float a0 = bias, a1 = 0.f;
#pragma unroll
        for (int k4 = 0; k4 < F / 4; ++k4) {
            float4 v = xr[k4];
            if (k4 & 1) {
                a1 += v.x * w[4 * k4 + 0]; a1 += v.y * w[4 * k4 + 1];
                a1 += v.z * w[4 * k4 + 2]; a1 += v.w * w[4 * k4 + 3];
            } else {
                a0 += v.x * w[4 * k4 + 0]; a0 += v.y * w[4 * k4 + 1];
                a0 += v.z * w[4 * k4 + 2]; a0 += v.w * w[4 * k4 + 3];
            }
        }
        float acc = a0 + a1;
        if (RELU) acc = fmaxf(acc, 0.0f);
        out[(size_t)node * 64 + lane] = acc;
    }
}

// Fused pair: two 64-wide linears over the SAME input, input row read once.
template <int F>
__global__ __launch_bounds__(256) void transform2_kernel(
    const float* __restrict__ in,
    const float* __restrict__ W0, const float* __restrict__ b0, float* __restrict__ out0,
    const float* __restrict__ W1, const float* __restrict__ b1, float* __restrict__ out1,
    int n)
{
    const int lane  = threadIdx.x & 63;
    const int wid   = (int)((blockIdx.x * (unsigned)blockDim.x + threadIdx.x) >> 6);
    const int nwav  = (int)((gridDim.x * (unsigned)blockDim.x) >> 6);

    float w0[F], w1[F];
    const float4* w0row = reinterpret_cast<const float4*>(W0 + (size_t)lane * F);
    const float4* w1row = reinterpret_cast<const float4*>(W1 + (size_t)lane * F);
#pragma unroll
    for (int k4 = 0; k4 < F / 4; ++k4) {
        float4 v = w0row[k4];
        w0[4 * k4 + 0] = v.x; w0[4 * k4 + 1] = v.y;
        w0[4 * k4 + 2] = v.z; w0[4 * k4 + 3] = v.w;
        float4 u = w1row[k4];
        w1[4 * k4 + 0] = u.x; w1[4 * k4 + 1] = u.y;
        w1[4 * k4 + 2] = u.z; w1[4 * k4 + 3] = u.w;
    }
    const float bias0 = b0[lane];
    const float bias1 = b1[lane];

    for (int node = wid; node < n; node += nwav) {
        const float4* xr = reinterpret_cast<const float4*>(in + (size_t)node * F);
        float a0 = bias0, a1 = 0.f;   // out0: two chains
        float c0 = bias1, c1 = 0.f;   // out1: two chains
#pragma unroll
        for (int k4 = 0; k4 < F / 4; ++k4) {
            float4 v = xr[k4];
            if (k4 & 1) {
                a1 += v.x * w0[4 * k4 + 0]; a1 += v.y * w0[4 * k4 + 1];
                a1 += v.z * w0[4 * k4 + 2]; a1 += v.w * w0[4 * k4 + 3];
                c1 += v.x * w1[4 * k4 + 0]; c1 += v.y * w1[4 * k4 + 1];
                c1 += v.z * w1[4 * k4 + 2]; c1 += v.w * w1[4 * k4 + 3];
            } else {
                a0 += v.x * w0[4 * k4 + 0]; a0 += v.y * w0[4 * k4 + 1];
                a0 += v.z * w0[4 * k4 + 2]; a0 += v.w * w0[4 * k4 + 3];
                c0 += v.x * w1[4 * k4 + 0]; c0 += v.y * w1[4 * k4 + 1];
                c0 += v.z * w1[4 * k4 + 2]; c0 += v.w * w1[4 * k4 + 3];
            }
        }
        out0[(size_t)node * 64 + lane] = fmaxf(a0 + a1, 0.0f);
        out1[(size_t)node * 64 + lane] = fmaxf(c0 + c1, 0.0f);
    }
}

// deg histogram over 3 concatenated dst lists
__global__ __launch_bounds__(256) void hist3_kernel(
    const int* __restrict__ d0, int E0,
    const int* __restrict__ d1, int E1,
    const int* __restrict__ d2, int E2,
    int* __restrict__ deg)
{
    const int total = E0 + E1 + E2;
    int i = blockIdx.x * blockDim.x + threadIdx.x;
    int stride = gridDim.x * blockDim.x;
    for (; i < total; i += stride) {
        int t;
        if (i < E0)            t = d0[i];
        else if (i < E0 + E1)  t = d1[i - E0];
        else                   t = d2[i - E0 - E1];
        atomicAdd(&deg[t], 1);
    }
}

// Exclusive scan deg -> offsets; zeroes deg afterwards (it becomes the cursor).
__global__ __launch_bounds__(1024) void scan_kernel(
    int* __restrict__ deg, int* __restrict__ offsets, int n)
{
    __shared__ int sums[1024];
    const int t = threadIdx.x;
    const int chunk = (n + 1023) / 1024;
    const int beg = t * chunk;
    const int end = min(n, beg + chunk);
    int s = 0;
    for (int i = beg; i < end; ++i) s += deg[i];
    sums[t] = s;
    __syncthreads();
    for (int off = 1; off < 1024; off <<= 1) {
        int v = (t >= off) ? sums[t - off] : 0;
        __syncthreads();
        sums[t] += v;
        __syncthreads();
    }
    int run = (t == 0) ? 0 : sums[t - 1];
    for (int i = beg; i < end; ++i) {
        offsets[i] = run;
        run += deg[i];
        deg[i] = 0;          // cursor init (saves a memset dispatch)
    }
    if (t == 0) offsets[n] = sums[1023];
}

// bucket-scatter of global H-row ids over 3 concatenated edge lists
__global__ __launch_bounds__(256) void bucket3_kernel(
    const int* __restrict__ s0, const int* __restrict__ d0, int E0, int base0,
    const int* __restrict__ s1, const int* __restrict__ d1, int E1, int base1,
    const int* __restrict__ s2, const int* __restrict__ d2, int E2, int base2,
    const int* __restrict__ offsets, int* __restrict__ cursor,
    int* __restrict__ rows)
{
    const int total = E0 + E1 + E2;
    int i = blockIdx.x * blockDim.x + threadIdx.x;
    int stride = gridDim.x * blockDim.x;
    for (; i < total; i += stride) {
        int t, v;
        if (i < E0)           { t = d0[i];           v = base0 + s0[i]; }
        else if (i < E0 + E1) { int k = i - E0;      t = d1[k]; v = base1 + s1[k]; }
        else                  { int k = i - E0 - E1; t = d2[k]; v = base2 + s2[k]; }
        int pos = offsets[t] + atomicAdd(&cursor[t], 1);
        rows[pos] = v;
    }
}

// agg[node] += sum of H[row] over in-edges. 8 loads in flight, 4 acc chains.
__global__ __launch_bounds__(256) void gather_kernel(
    const int* __restrict__ offsets, const int* __restrict__ rows,
    const float* __restrict__ H, float* __restrict__ agg, int n)
{
    const int lane  = threadIdx.x & 63;
    const int wid   = (int)((blockIdx.x * (unsigned)blockDim.x + threadIdx.x) >> 6);
    const int nwav  = (int)((gridDim.x * (unsigned)blockDim.x) >> 6);
    const float* Hl = H + lane;

    for (int node = wid; node < n; node += nwav) {
        const int beg = offsets[node];
        const int end = offsets[node + 1];
        float acc0 = agg[(size_t)node * 64 + lane];
        float acc1 = 0.f, acc2 = 0.f, acc3 = 0.f;
        int o = beg;
        while (o < end) {
            const int m = min(64, end - o);
            int idx = (lane < m) ? rows[o + lane] : 0;
            int j = 0;
            for (; j + 8 <= m; j += 8) {
                int r0 = __shfl(idx, j + 0), r1 = __shfl(idx, j + 1);
                int r2 = __shfl(idx, j + 2), r3 = __shfl(idx, j + 3);
                int r4 = __shfl(idx, j + 4), r5 = __shfl(idx, j + 5);
                int r6 = __shfl(idx, j + 6), r7 = __shfl(idx, j + 7);
                float v0 = Hl[(size_t)r0 * 64];
                float v1 = Hl[(size_t)r1 * 64];
                float v2 = Hl[(size_t)r2 * 64];
                float v3 = Hl[(size_t)r3 * 64];
                float v4 = Hl[(size_t)r4 * 64];
                float v5 = Hl[(size_t)r5 * 64];
                float v6 = Hl[(size_t)r6 * 64];
                float v7 = Hl[(size_t)r7 * 64];
                acc0 += v0; acc1 += v1; acc2 += v2; acc3 += v3;
                acc0 += v4; acc1 += v5; acc2 += v6; acc3 += v7;
            }
            for (; j < m; ++j)
                acc0 += Hl[(size_t)__shfl(idx, j) * 64];
            o += m;
        }
        agg[(size_t)node * 64 + lane] = (acc0 + acc1) + (acc2 + acc3);
    }
}

extern "C" void kernel_launch(void* const* d_in, const int* in_sizes, int n_in,
                              void* d_out, int out_size, void* d_ws, size_t ws_size,
                              hipStream_t stream)
{
    const float* x = (const float*)d_in[0];
    const float* c = (const float*)d_in[1];
    const float* r = (const float*)d_in[2];
    const int* exx_s = (const int*)d_in[3];
    const int* exx_d = (const int*)d_in[4];
    const int* ecx_s = (const int*)d_in[5];
    const int* ecx_d = (const int*)d_in[6];
    const int* erx_s = (const int*)d_in[7];
    const int* erx_d = (const int*)d_in[8];
    const float* W_x  = (const float*)d_in[9];
    const float* b_x  = (const float*)d_in[10];
    const float* W_c  = (const float*)d_in[11];
    const float* b_c  = (const float*)d_in[12];
    const float* W_r  = (const float*)d_in[13];
    const float* b_r  = (const float*)d_in[14];
    const float* W_xx = (const float*)d_in[15];
    const float* b_xx = (const float*)d_in[16];
    const float* W_cx = (const float*)d_in[17];
    const float* b_cx = (const float*)d_in[18];
    const float* W_rx = (const float*)d_in[19];
    const float* b_rx = (const float*)d_in[20];
    const float* W_pool = (const float*)d_in[21];
    const float* b_pool = (const float*)d_in[22];

    const int N_x = in_sizes[0] / 64;
    const int N_c = in_sizes[1] / 32;
    const int N_r = in_sizes[2] / 48;
    const int E_xx = in_sizes[3];
    const int E_cx = in_sizes[5];
    const int E_rx = in_sizes[7];

    // workspace layout
    float* ws   = (float*)d_ws;
    float* agg  = ws;                                   // [N_x][64]
    float* H    = agg + (size_t)N_x * 64;               // [(N_x+N_c+N_r)][64]
    float* h_xx = H;
    float* h_cx = H + (size_t)N_x * 64;
    float* h_rx = H + (size_t)(N_x + N_c) * 64;
    int*   deg     = (int*)(H + (size_t)(N_x + N_c + N_r) * 64);  // [N_x] (also cursor)
    int*   offsets = deg + N_x;                         // [N_x+1]
    int*   rows    = offsets + N_x + 1;                 // [E_xx+E_cx+E_rx]

    float* out_x = (float*)d_out;                       // [N_x][64]
    float* out_c = out_x + (size_t)N_x * 64;            // [N_c][64]
    float* out_r = out_c + (size_t)N_c * 64;            // [N_r][64]

    const int BLK = 256;
    const int TGRID = 2048;
    const int EGRID = 1024;

    // fused per-node transforms: each input read once
    transform2_kernel<64><<<TGRID, BLK, 0, stream>>>(x, W_x, b_x, agg,  W_xx, b_xx, h_xx, N_x);
    transform2_kernel<32><<<TGRID, BLK, 0, stream>>>(c, W_c, b_c, out_c, W_cx, b_cx, h_cx, N_c);
    transform2_kernel<48><<<TGRID, BLK, 0, stream>>>(r, W_r, b_r, out_r, W_rx, b_rx, h_rx, N_r);

    // combined CSR over all 3 relations
    hipMemsetAsync(deg, 0, (size_t)N_x * sizeof(int), stream);
    hist3_kernel<<<EGRID, BLK, 0, stream>>>(exx_d, E_xx, ecx_d, E_cx, erx_d, E_rx, deg);
    scan_kernel<<<1, 1024, 0, stream>>>(deg, offsets, N_x);   // also zeroes deg -> cursor
    bucket3_kernel<<<EGRID, BLK, 0, stream>>>(
        exx_s, exx_d, E_xx, 0,
        ecx_s, ecx_d, E_cx, N_x,
        erx_s, erx_d, E_rx, N_x + N_c,
        offsets, deg, rows);

    // atomic-free accumulate (8-deep load pipeline)
    gather_kernel<<<TGRID, BLK, 0, stream>>>(offsets, rows, H, agg, N_x);

    // x_out = agg @ W_pool^T + b_pool
    transform_kernel<64, false><<<TGRID, BLK, 0, stream>>>(agg, W_pool, b_pool, out_x, N_x);
}

// Round 6
// 885.421 us; speedup vs baseline: 1.9610x; 1.2445x over previous
//
#include <hip/hip_runtime.h>
#include <hip/hip_bf16.h>

// ---------------------------------------------------------------------------
// CondGCN round 6:
//  - r5 counters: scan_kernel = 229us @ 0.149% occupancy (single-block serial
//    scan on 1 CU). Replaced with 3-phase multi-block scan (~15us total).
//  - everything else unchanged from r5 so the next profile cleanly exposes
//    the true cost distribution (gather / bucket3 / transforms).
// ---------------------------------------------------------------------------

// Single transform: out[n][64] = (relu?)(in[n][F] @ W^T + b)
template <int F, bool RELU>
__global__ __launch_bounds__(256) void transform_kernel(
    const float* __restrict__ in, const float* __restrict__ W,
    const float* __restrict__ b, float* __restrict__ out, int n)
{
    const int lane  = threadIdx.x & 63;
    const int wid   = (int)((blockIdx.x * (unsigned)blockDim.x + threadIdx.x) >> 6);
    const int nwav  = (int)((gridDim.x * (unsigned)blockDim.x) >> 6);

    float w[F];
    const float4* wrow = reinterpret_cast<const float4*>(W + (size_t)lane * F);
#pragma unroll
    for (int k4 = 0; k4 < F / 4; ++k4) {
        float4 v = wrow[k4];
        w[4 * k4 + 0] = v.x; w[4 * k4 + 1] = v.y;
        w[4 * k4 + 2] = v.z; w[4 * k4 + 3] = v.w;
    }
    const float bias = b[lane];

    for (int node = wid; node < n; node += nwav) {
        const float4* xr = reinterpret_cast<const float4*>(in + (size_t)node * F);
        float a0 = bias, a1 = 0.f;
#pragma unroll
        for (int k4 = 0; k4 < F / 4; ++k4) {
            float4 v = xr[k4];
            if (k4 & 1) {
                a1 += v.x * w[4 * k4 + 0]; a1 += v.y * w[4 * k4 + 1];
                a1 += v.z * w[4 * k4 + 2]; a1 += v.w * w[4 * k4 + 3];
            } else {
                a0 += v.x * w[4 * k4 + 0]; a0 += v.y * w[4 * k4 + 1];
                a0 += v.z * w[4 * k4 + 2]; a0 += v.w * w[4 * k4 + 3];
            }
        }
        float acc = a0 + a1;
        if (RELU) acc = fmaxf(acc, 0.0f);
        out[(size_t)node * 64 + lane] = acc;
    }
}

// Fused pair: two 64-wide linears over the SAME input, input row read once.
template <int F>
__global__ __launch_bounds__(256) void transform2_kernel(
    const float* __restrict__ in,
    const float* __restrict__ W0, const float* __restrict__ b0, float* __restrict__ out0,
    const float* __restrict__ W1, const float* __restrict__ b1, float* __restrict__ out1,
    int n)
{
    const int lane  = threadIdx.x & 63;
    const int wid   = (int)((blockIdx.x * (unsigned)blockDim.x + threadIdx.x) >> 6);
    const int nwav  = (int)((gridDim.x * (unsigned)blockDim.x) >> 6);

    float w0[F], w1[F];
    const float4* w0row = reinterpret_cast<const float4*>(W0 + (size_t)lane * F);
    const float4* w1row = reinterpret_cast<const float4*>(W1 + (size_t)lane * F);
#pragma unroll
    for (int k4 = 0; k4 < F / 4; ++k4) {
        float4 v = w0row[k4];
        w0[4 * k4 + 0] = v.x; w0[4 * k4 + 1] = v.y;
        w0[4 * k4 + 2] = v.z; w0[4 * k4 + 3] = v.w;
        float4 u = w1row[k4];
        w1[4 * k4 + 0] = u.x; w1[4 * k4 + 1] = u.y;
        w1[4 * k4 + 2] = u.z; w1[4 * k4 + 3] = u.w;
    }
    const float bias0 = b0[lane];
    const float bias1 = b1[lane];

    for (int node = wid; node < n; node += nwav) {
        const float4* xr = reinterpret_cast<const float4*>(in + (size_t)node * F);
        float a0 = bias0, a1 = 0.f;
        float c0 = bias1, c1 = 0.f;
#pragma unroll
        for (int k4 = 0; k4 < F / 4; ++k4) {
            float4 v = xr[k4];
            if (k4 & 1) {
                a1 += v.x * w0[4 * k4 + 0]; a1 += v.y * w0[4 * k4 + 1];
                a1 += v.z * w0[4 * k4 + 2]; a1 += v.w * w0[4 * k4 + 3];
                c1 += v.x * w1[4 * k4 + 0]; c1 += v.y * w1[4 * k4 + 1];
                c1 += v.z * w1[4 * k4 + 2]; c1 += v.w * w1[4 * k4 + 3];
            } else {
                a0 += v.x * w0[4 * k4 + 0]; a0 += v.y * w0[4 * k4 + 1];
                a0 += v.z * w0[4 * k4 + 2]; a0 += v.w * w0[4 * k4 + 3];
                c0 += v.x * w1[4 * k4 + 0]; c0 += v.y * w1[4 * k4 + 1];
                c0 += v.z * w1[4 * k4 + 2]; c0 += v.w * w1[4 * k4 + 3];
            }
        }
        out0[(size_t)node * 64 + lane] = fmaxf(a0 + a1, 0.0f);
        out1[(size_t)node * 64 + lane] = fmaxf(c0 + c1, 0.0f);
    }
}

// deg histogram over 3 concatenated dst lists
__global__ __launch_bounds__(256) void hist3_kernel(
    const int* __restrict__ d0, int E0,
    const int* __restrict__ d1, int E1,
    const int* __restrict__ d2, int E2,
    int* __restrict__ deg)
{
    const int total = E0 + E1 + E2;
    int i = blockIdx.x * blockDim.x + threadIdx.x;
    int stride = gridDim.x * blockDim.x;
    for (; i < total; i += stride) {
        int t;
        if (i < E0)            t = d0[i];
        else if (i < E0 + E1)  t = d1[i - E0];
        else                   t = d2[i - E0 - E1];
        atomicAdd(&deg[t], 1);
    }
}

// ------------------- 3-phase device-wide exclusive scan --------------------
#define SCAN_BLOCKS 256

// Phase A: per-block partial sum of its contiguous tile.
__global__ __launch_bounds__(256) void scan_partial_kernel(
    const int* __restrict__ deg, int n, int* __restrict__ bsum)
{
    __shared__ int red[256];
    const int tile = (n + SCAN_BLOCKS - 1) / SCAN_BLOCKS;
    const int beg = blockIdx.x * tile;
    const int end = min(n, beg + tile);
    int s = 0;
    for (int i = beg + threadIdx.x; i < end; i += 256) s += deg[i];
    red[threadIdx.x] = s;
    __syncthreads();
    for (int off = 128; off > 0; off >>= 1) {
        if (threadIdx.x < off) red[threadIdx.x] += red[threadIdx.x + off];
        __syncthreads();
    }
    if (threadIdx.x == 0) bsum[blockIdx.x] = red[0];
}

// Phase B: one block scans the SCAN_BLOCKS block sums; writes offsets[n]=total.
__global__ __launch_bounds__(SCAN_BLOCKS) void scan_blocksums_kernel(
    const int* __restrict__ bsum, int* __restrict__ bbase,
    int* __restrict__ offsets, int n)
{
    __shared__ int sh[SCAN_BLOCKS];
    const int t = threadIdx.x;
    sh[t] = bsum[t];
    __syncthreads();
    for (int off = 1; off < SCAN_BLOCKS; off <<= 1) {
        int v = (t >= off) ? sh[t - off] : 0;
        __syncthreads();
        sh[t] += v;
        __syncthreads();
    }
    bbase[t] = (t == 0) ? 0 : sh[t - 1];
    if (t == SCAN_BLOCKS - 1) offsets[n] = sh[t];
}

// Phase C: per-block exclusive scan of its tile; writes offsets, zeroes deg
// (deg becomes the bucket cursor).
__global__ __launch_bounds__(256) void scan_write_kernel(
    int* __restrict__ deg, int* __restrict__ offsets,
    const int* __restrict__ bbase, int n)
{
    __shared__ int tsum[256];
    const int tile = (n + SCAN_BLOCKS - 1) / SCAN_BLOCKS;
    const int beg = blockIdx.x * tile;
    const int end = min(n, beg + tile);
    const int chunk = (tile + 255) / 256;
    const int tb = beg + threadIdx.x * chunk;
    const int te = min(end, tb + chunk);
    int s = 0;
    for (int i = tb; i < te; ++i) s += deg[i];
    tsum[threadIdx.x] = s;
    __syncthreads();
    for (int off = 1; off < 256; off <<= 1) {
        int v = (threadIdx.x >= off) ? tsum[threadIdx.x - off] : 0;
        __syncthreads();
        tsum[threadIdx.x] += v;
        __syncthreads();
    }
    int run = bbase[blockIdx.x] + ((threadIdx.x == 0) ? 0 : tsum[threadIdx.x - 1]);
    for (int i = tb; i < te; ++i) {
        offsets[i] = run;
        run += deg[i];
        deg[i] = 0;
    }
}

// bucket-scatter of global H-row ids over 3 concatenated edge lists
__global__ __launch_bounds__(256) void bucket3_kernel(
    const int* __restrict__ s0, const int* __restrict__ d0, int E0, int base0,
    const int* __restrict__ s1, const int* __restrict__ d1, int E1, int base1,
    const int* __restrict__ s2, const int* __restrict__ d2, int E2, int base2,
    const int* __restrict__ offsets, int* __restrict__ cursor,
    int* __restrict__ rows)
{
    const int total = E0 + E1 + E2;
    int i = blockIdx.x * blockDim.x + threadIdx.x;
    int stride = gridDim.x * blockDim.x;
    for (; i < total; i += stride) {
        int t, v;
        if (i < E0)           { t = d0[i];           v = base0 + s0[i]; }
        else if (i < E0 + E1) { int k = i - E0;      t = d1[k]; v = base1 + s1[k]; }
        else                  { int k = i - E0 - E1; t = d2[k]; v = base2 + s2[k]; }
        int pos = offsets[t] + atomicAdd(&cursor[t], 1);
        rows[pos] = v;
    }
}

// agg[node] += sum of H[row] over in-edges. 8 loads in flight, 4 acc chains.
__global__ __launch_bounds__(256) void gather_kernel(
    const int* __restrict__ offsets, const int* __restrict__ rows,
    const float* __restrict__ H, float* __restrict__ agg, int n)
{
    const int lane  = threadIdx.x & 63;
    const int wid   = (int)((blockIdx.x * (unsigned)blockDim.x + threadIdx.x) >> 6);
    const int nwav  = (int)((gridDim.x * (unsigned)blockDim.x) >> 6);
    const float* Hl = H + lane;

    for (int node = wid; node < n; node += nwav) {
        const int beg = offsets[node];
        const int end = offsets[node + 1];
        float acc0 = agg[(size_t)node * 64 + lane];
        float acc1 = 0.f, acc2 = 0.f, acc3 = 0.f;
        int o = beg;
        while (o < end) {
            const int m = min(64, end - o);
            int idx = (lane < m) ? rows[o + lane] : 0;
            int j = 0;
            for (; j + 8 <= m; j += 8) {
                int r0 = __shfl(idx, j + 0), r1 = __shfl(idx, j + 1);
                int r2 = __shfl(idx, j + 2), r3 = __shfl(idx, j + 3);
                int r4 = __shfl(idx, j + 4), r5 = __shfl(idx, j + 5);
                int r6 = __shfl(idx, j + 6), r7 = __shfl(idx, j + 7);
                float v0 = Hl[(size_t)r0 * 64];
                float v1 = Hl[(size_t)r1 * 64];
                float v2 = Hl[(size_t)r2 * 64];
                float v3 = Hl[(size_t)r3 * 64];
                float v4 = Hl[(size_t)r4 * 64];
                float v5 = Hl[(size_t)r5 * 64];
                float v6 = Hl[(size_t)r6 * 64];
                float v7 = Hl[(size_t)r7 * 64];
                acc0 += v0; acc1 += v1; acc2 += v2; acc3 += v3;
                acc0 += v4; acc1 += v5; acc2 += v6; acc3 += v7;
            }
            for (; j < m; ++j)
                acc0 += Hl[(size_t)__shfl(idx, j) * 64];
            o += m;
        }
        agg[(size_t)node * 64 + lane] = (acc0 + acc1) + (acc2 + acc3);
    }
}

extern "C" void kernel_launch(void* const* d_in, const int* in_sizes, int n_in,
                              void* d_out, int out_size, void* d_ws, size_t ws_size,
                              hipStream_t stream)
{
    const float* x = (const float*)d_in[0];
    const float* c = (const float*)d_in[1];
    const float* r = (const float*)d_in[2];
    const int* exx_s = (const int*)d_in[3];
    const int* exx_d = (const int*)d_in[4];
    const int* ecx_s = (const int*)d_in[5];
    const int* ecx_d = (const int*)d_in[6];
    const int* erx_s = (const int*)d_in[7];
    const int* erx_d = (const int*)d_in[8];
    const float* W_x  = (const float*)d_in[9];
    const float* b_x  = (const float*)d_in[10];
    const float* W_c  = (const float*)d_in[11];
    const float* b_c  = (const float*)d_in[12];
    const float* W_r  = (const float*)d_in[13];
    const float* b_r  = (const float*)d_in[14];
    const float* W_xx = (const float*)d_in[15];
    const float* b_xx = (const float*)d_in[16];
    const float* W_cx = (const float*)d_in[17];
    const float* b_cx = (const float*)d_in[18];
    const float* W_rx = (const float*)d_in[19];
    const float* b_rx = (const float*)d_in[20];
    const float* W_pool = (const float*)d_in[21];
    const float* b_pool = (const float*)d_in[22];

    const int N_x = in_sizes[0] / 64;
    const int N_c = in_sizes[1] / 32;
    const int N_r = in_sizes[2] / 48;
    const int E_xx = in_sizes[3];
    const int E_cx = in_sizes[5];
    const int E_rx = in_sizes[7];
    const int E_total = E_xx + E_cx + E_rx;

    // workspace layout
    float* ws   = (float*)d_ws;
    float* agg  = ws;                                   // [N_x][64]
    float* H    = agg + (size_t)N_x * 64;               // [(N_x+N_c+N_r)][64]
    float* h_xx = H;
    float* h_cx = H + (size_t)N_x * 64;
    float* h_rx = H + (size_t)(N_x + N_c) * 64;
    int*   deg     = (int*)(H + (size_t)(N_x + N_c + N_r) * 64);  // [N_x] (also cursor)
    int*   offsets = deg + N_x;                         // [N_x+1]
    int*   rows    = offsets + N_x + 1;                 // [E_total]
    int*   bsum    = rows + E_total;                    // [SCAN_BLOCKS]
    int*   bbase   = bsum + SCAN_BLOCKS;                // [SCAN_BLOCKS]

    float* out_x = (float*)d_out;                       // [N_x][64]
    float* out_c = out_x + (size_t)N_x * 64;            // [N_c][64]
    float* out_r = out_c + (size_t)N_c * 64;            // [N_r][64]

    const int BLK = 256;
    const int TGRID = 2048;
    const int EGRID = 1024;

    // fused per-node transforms: each input read once
    transform2_kernel<64><<<TGRID, BLK, 0, stream>>>(x, W_x, b_x, agg,  W_xx, b_xx, h_xx, N_x);
    transform2_kernel<32><<<TGRID, BLK, 0, stream>>>(c, W_c, b_c, out_c, W_cx, b_cx, h_cx, N_c);
    transform2_kernel<48><<<TGRID, BLK, 0, stream>>>(r, W_r, b_r, out_r, W_rx, b_rx, h_rx, N_r);

    // combined CSR over all 3 relations
    hipMemsetAsync(deg, 0, (size_t)N_x * sizeof(int), stream);
    hist3_kernel<<<EGRID, BLK, 0, stream>>>(exx_d, E_xx, ecx_d, E_cx, erx_d, E_rx, deg);
    // 3-phase parallel scan (replaces 229us single-block scan)
    scan_partial_kernel  <<<SCAN_BLOCKS, 256, 0, stream>>>(deg, N_x, bsum);
    scan_blocksums_kernel<<<1, SCAN_BLOCKS, 0, stream>>>(bsum, bbase, offsets, N_x);
    scan_write_kernel    <<<SCAN_BLOCKS, 256, 0, stream>>>(deg, offsets, bbase, N_x);
    bucket3_kernel<<<EGRID, BLK, 0, stream>>>(
        exx_s, exx_d, E_xx, 0,
        ecx_s, ecx_d, E_cx, N_x,
        erx_s, erx_d, E_rx, N_x + N_c,
        offsets, deg, rows);

    // atomic-free accumulate (8-deep load pipeline)
    gather_kernel<<<TGRID, BLK, 0, stream>>>(offsets, rows, H, agg, N_x);

    // x_out = agg @ W_pool^T + b_pool
    transform_kernel<64, false><<<TGRID, BLK, 0, stream>>>(agg, W_pool, b_pool, out_x, N_x);
}

// Round 7
// 801.855 us; speedup vs baseline: 2.1653x; 1.1042x over previous
//
#include <hip/hip_runtime.h>
#include <hip/hip_bf16.h>

// ---------------------------------------------------------------------------
// CondGCN round 7:
//  - r6 counters: transform2<64> = 200us @ VGPR=224, occ 10.7%, VALU 17.8%,
//    HBM 4% -> W-pair-in-VGPR fusion killed occupancy; latency unhidden.
//    UNFUSED back to single-W transforms (~110 VGPR, 4 waves/SIMD).
//  - pool pass fused into gather: agg row is already in registers at the end
//    of the edge accumulation; per-wave LDS exchange + W_pool-in-VGPR dot
//    writes out_x directly (saves a whole 100K x 64 pass, ~110us).
//  - CSR build (hist3 / 3-phase scan / bucket3) unchanged.
// ---------------------------------------------------------------------------

// Single transform: out[n][64] = (relu?)(in[n][F] @ W^T + b)
// Lane = output dim; W row in VGPRs; input row via wave-uniform broadcast.
template <int F, bool RELU>
__global__ __launch_bounds__(256) void transform_kernel(
    const float* __restrict__ in, const float* __restrict__ W,
    const float* __restrict__ b, float* __restrict__ out, int n)
{
    const int lane  = threadIdx.x & 63;
    const int wid   = (int)((blockIdx.x * (unsigned)blockDim.x + threadIdx.x) >> 6);
    const int nwav  = (int)((gridDim.x * (unsigned)blockDim.x) >> 6);

    float w[F];
    const float4* wrow = reinterpret_cast<const float4*>(W + (size_t)lane * F);
#pragma unroll
    for (int k4 = 0; k4 < F / 4; ++k4) {
        float4 v = wrow[k4];
        w[4 * k4 + 0] = v.x; w[4 * k4 + 1] = v.y;
        w[4 * k4 + 2] = v.z; w[4 * k4 + 3] = v.w;
    }
    const float bias = b[lane];

    for (int node = wid; node < n; node += nwav) {
        const float4* xr = reinterpret_cast<const float4*>(in + (size_t)node * F);
        float a0 = bias, a1 = 0.f;
#pragma unroll
        for (int k4 = 0; k4 < F / 4; ++k4) {
            float4 v = xr[k4];
            if (k4 & 1) {
                a1 += v.x * w[4 * k4 + 0]; a1 += v.y * w[4 * k4 + 1];
                a1 += v.z * w[4 * k4 + 2]; a1 += v.w * w[4 * k4 + 3];
            } else {
                a0 += v.x * w[4 * k4 + 0]; a0 += v.y * w[4 * k4 + 1];
                a0 += v.z * w[4 * k4 + 2]; a0 += v.w * w[4 * k4 + 3];
            }
        }
        float acc = a0 + a1;
        if (RELU) acc = fmaxf(acc, 0.0f);
        out[(size_t)node * 64 + lane] = acc;
    }
}

// deg histogram over 3 concatenated dst lists
__global__ __launch_bounds__(256) void hist3_kernel(
    const int* __restrict__ d0, int E0,
    const int* __restrict__ d1, int E1,
    const int* __restrict__ d2, int E2,
    int* __restrict__ deg)
{
    const int total = E0 + E1 + E2;
    int i = blockIdx.x * blockDim.x + threadIdx.x;
    int stride = gridDim.x * blockDim.x;
    for (; i < total; i += stride) {
        int t;
        if (i < E0)            t = d0[i];
        else if (i < E0 + E1)  t = d1[i - E0];
        else                   t = d2[i - E0 - E1];
        atomicAdd(&deg[t], 1);
    }
}

// ------------------- 3-phase device-wide exclusive scan --------------------
#define SCAN_BLOCKS 256

__global__ __launch_bounds__(256) void scan_partial_kernel(
    const int* __restrict__ deg, int n, int* __restrict__ bsum)
{
    __shared__ int red[256];
    const int tile = (n + SCAN_BLOCKS - 1) / SCAN_BLOCKS;
    const int beg = blockIdx.x * tile;
    const int end = min(n, beg + tile);
    int s = 0;
    for (int i = beg + threadIdx.x; i < end; i += 256) s += deg[i];
    red[threadIdx.x] = s;
    __syncthreads();
    for (int off = 128; off > 0; off >>= 1) {
        if (threadIdx.x < off) red[threadIdx.x] += red[threadIdx.x + off];
        __syncthreads();
    }
    if (threadIdx.x == 0) bsum[blockIdx.x] = red[0];
}

__global__ __launch_bounds__(SCAN_BLOCKS) void scan_blocksums_kernel(
    const int* __restrict__ bsum, int* __restrict__ bbase,
    int* __restrict__ offsets, int n)
{
    __shared__ int sh[SCAN_BLOCKS];
    const int t = threadIdx.x;
    sh[t] = bsum[t];
    __syncthreads();
    for (int off = 1; off < SCAN_BLOCKS; off <<= 1) {
        int v = (t >= off) ? sh[t - off] : 0;
        __syncthreads();
        sh[t] += v;
        __syncthreads();
    }
    bbase[t] = (t == 0) ? 0 : sh[t - 1];
    if (t == SCAN_BLOCKS - 1) offsets[n] = sh[t];
}

__global__ __launch_bounds__(256) void scan_write_kernel(
    int* __restrict__ deg, int* __restrict__ offsets,
    const int* __restrict__ bbase, int n)
{
    __shared__ int tsum[256];
    const int tile = (n + SCAN_BLOCKS - 1) / SCAN_BLOCKS;
    const int beg = blockIdx.x * tile;
    const int end = min(n, beg + tile);
    const int chunk = (tile + 255) / 256;
    const int tb = beg + threadIdx.x * chunk;
    const int te = min(end, tb + chunk);
    int s = 0;
    for (int i = tb; i < te; ++i) s += deg[i];
    tsum[threadIdx.x] = s;
    __syncthreads();
    for (int off = 1; off < 256; off <<= 1) {
        int v = (threadIdx.x >= off) ? tsum[threadIdx.x - off] : 0;
        __syncthreads();
        tsum[threadIdx.x] += v;
        __syncthreads();
    }
    int run = bbase[blockIdx.x] + ((threadIdx.x == 0) ? 0 : tsum[threadIdx.x - 1]);
    for (int i = tb; i < te; ++i) {
        offsets[i] = run;
        run += deg[i];
        deg[i] = 0;
    }
}

// bucket-scatter of global H-row ids over 3 concatenated edge lists
__global__ __launch_bounds__(256) void bucket3_kernel(
    const int* __restrict__ s0, const int* __restrict__ d0, int E0, int base0,
    const int* __restrict__ s1, const int* __restrict__ d1, int E1, int base1,
    const int* __restrict__ s2, const int* __restrict__ d2, int E2, int base2,
    const int* __restrict__ offsets, int* __restrict__ cursor,
    int* __restrict__ rows)
{
    const int total = E0 + E1 + E2;
    int i = blockIdx.x * blockDim.x + threadIdx.x;
    int stride = gridDim.x * blockDim.x;
    for (; i < total; i += stride) {
        int t, v;
        if (i < E0)           { t = d0[i];           v = base0 + s0[i]; }
        else if (i < E0 + E1) { int k = i - E0;      t = d1[k]; v = base1 + s1[k]; }
        else                  { int k = i - E0 - E1; t = d2[k]; v = base2 + s2[k]; }
        int pos = offsets[t] + atomicAdd(&cursor[t], 1);
        rows[pos] = v;
    }
}

// Fused gather + pool:
//   row = agg_self[node] + sum_{in-edges} H[row_id]      (registers, lane=dim)
//   out_x[node] = W_pool @ row + b_pool                  (per-wave LDS exchange)
__global__ __launch_bounds__(256) void gather_pool_kernel(
    const int* __restrict__ offsets, const int* __restrict__ rows,
    const float* __restrict__ H, const float* __restrict__ agg_self,
    const float* __restrict__ W_pool, const float* __restrict__ b_pool,
    float* __restrict__ out_x, int n)
{
    __shared__ float srow[4][64];          // one 256B slot per wave
    const int lane  = threadIdx.x & 63;
    const int wslot = threadIdx.x >> 6;
    const int wid   = (int)((blockIdx.x * (unsigned)blockDim.x + threadIdx.x) >> 6);
    const int nwav  = (int)((gridDim.x * (unsigned)blockDim.x) >> 6);
    const float* Hl = H + lane;

    // W_pool row for this lane (output dim = lane), 64 floats in VGPRs
    float wp[64];
    const float4* wrow = reinterpret_cast<const float4*>(W_pool + (size_t)lane * 64);
#pragma unroll
    for (int k4 = 0; k4 < 16; ++k4) {
        float4 v = wrow[k4];
        wp[4 * k4 + 0] = v.x; wp[4 * k4 + 1] = v.y;
        wp[4 * k4 + 2] = v.z; wp[4 * k4 + 3] = v.w;
    }
    const float bias = b_pool[lane];

    for (int node = wid; node < n; node += nwav) {
        const int beg = offsets[node];
        const int end = offsets[node + 1];
        float acc0 = agg_self[(size_t)node * 64 + lane];
        float acc1 = 0.f, acc2 = 0.f, acc3 = 0.f;
        int o = beg;
        while (o < end) {
            const int m = min(64, end - o);
            int idx = (lane < m) ? rows[o + lane] : 0;
            int j = 0;
            for (; j + 8 <= m; j += 8) {
                int r0 = __shfl(idx, j + 0), r1 = __shfl(idx, j + 1);
                int r2 = __shfl(idx, j + 2), r3 = __shfl(idx, j + 3);
                int r4 = __shfl(idx, j + 4), r5 = __shfl(idx, j + 5);
                int r6 = __shfl(idx, j + 6), r7 = __shfl(idx, j + 7);
                float v0 = Hl[(size_t)r0 * 64];
                float v1 = Hl[(size_t)r1 * 64];
                float v2 = Hl[(size_t)r2 * 64];
                float v3 = Hl[(size_t)r3 * 64];
                float v4 = Hl[(size_t)r4 * 64];
                float v5 = Hl[(size_t)r5 * 64];
                float v6 = Hl[(size_t)r6 * 64];
                float v7 = Hl[(size_t)r7 * 64];
                acc0 += v0; acc1 += v1; acc2 += v2; acc3 += v3;
                acc0 += v4; acc1 += v5; acc2 += v6; acc3 += v7;
            }
            for (; j < m; ++j)
                acc0 += Hl[(size_t)__shfl(idx, j) * 64];
            o += m;
        }
        const float rowv = (acc0 + acc1) + (acc2 + acc3);

        // per-wave exchange: lane d publishes row[d], then every lane reads
        // the full row (broadcast b128 reads) and dots with its W_pool row.
        srow[wslot][lane] = rowv;
        asm volatile("s_waitcnt lgkmcnt(0)" ::: "memory");
        __builtin_amdgcn_sched_barrier(0);
        const float4* sr = reinterpret_cast<const float4*>(srow[wslot]);
        float p0 = bias, p1 = 0.f;
#pragma unroll
        for (int k4 = 0; k4 < 16; ++k4) {
            float4 v = sr[k4];
            if (k4 & 1) {
                p1 += v.x * wp[4 * k4 + 0]; p1 += v.y * wp[4 * k4 + 1];
                p1 += v.z * wp[4 * k4 + 2]; p1 += v.w * wp[4 * k4 + 3];
            } else {
                p0 += v.x * wp[4 * k4 + 0]; p0 += v.y * wp[4 * k4 + 1];
                p0 += v.z * wp[4 * k4 + 2]; p0 += v.w * wp[4 * k4 + 3];
            }
        }
        out_x[(size_t)node * 64 + lane] = p0 + p1;
    }
}

extern "C" void kernel_launch(void* const* d_in, const int* in_sizes, int n_in,
                              void* d_out, int out_size, void* d_ws, size_t ws_size,
                              hipStream_t stream)
{
    const float* x = (const float*)d_in[0];
    const float* c = (const float*)d_in[1];
    const float* r = (const float*)d_in[2];
    const int* exx_s = (const int*)d_in[3];
    const int* exx_d = (const int*)d_in[4];
    const int* ecx_s = (const int*)d_in[5];
    const int* ecx_d = (const int*)d_in[6];
    const int* erx_s = (const int*)d_in[7];
    const int* erx_d = (const int*)d_in[8];
    const float* W_x  = (const float*)d_in[9];
    const float* b_x  = (const float*)d_in[10];
    const float* W_c  = (const float*)d_in[11];
    const float* b_c  = (const float*)d_in[12];
    const float* W_r  = (const float*)d_in[13];
    const float* b_r  = (const float*)d_in[14];
    const float* W_xx = (const float*)d_in[15];
    const float* b_xx = (const float*)d_in[16];
    const float* W_cx = (const float*)d_in[17];
    const float* b_cx = (const float*)d_in[18];
    const float* W_rx = (const float*)d_in[19];
    const float* b_rx = (const float*)d_in[20];
    const float* W_pool = (const float*)d_in[21];
    const float* b_pool = (const float*)d_in[22];

    const int N_x = in_sizes[0] / 64;
    const int N_c = in_sizes[1] / 32;
    const int N_r = in_sizes[2] / 48;
    const int E_xx = in_sizes[3];
    const int E_cx = in_sizes[5];
    const int E_rx = in_sizes[7];
    const int E_total = E_xx + E_cx + E_rx;

    // workspace layout
    float* ws   = (float*)d_ws;
    float* agg  = ws;                                   // [N_x][64] self-loop term
    float* H    = agg + (size_t)N_x * 64;               // [(N_x+N_c+N_r)][64]
    float* h_xx = H;
    float* h_cx = H + (size_t)N_x * 64;
    float* h_rx = H + (size_t)(N_x + N_c) * 64;
    int*   deg     = (int*)(H + (size_t)(N_x + N_c + N_r) * 64);  // [N_x] (also cursor)
    int*   offsets = deg + N_x;                         // [N_x+1]
    int*   rows    = offsets + N_x + 1;                 // [E_total]
    int*   bsum    = rows + E_total;                    // [SCAN_BLOCKS]
    int*   bbase   = bsum + SCAN_BLOCKS;                // [SCAN_BLOCKS]

    float* out_x = (float*)d_out;                       // [N_x][64]
    float* out_c = out_x + (size_t)N_x * 64;            // [N_c][64]
    float* out_r = out_c + (size_t)N_c * 64;            // [N_r][64]

    const int BLK = 256;
    const int TGRID = 1024;   // ~resident-wave count at 4 waves/SIMD
    const int EGRID = 1024;

    // per-node transforms, UNFUSED (one W tile per lane -> high occupancy)
    transform_kernel<64, true><<<TGRID, BLK, 0, stream>>>(x, W_x,  b_x,  agg,  N_x);
    transform_kernel<64, true><<<TGRID, BLK, 0, stream>>>(x, W_xx, b_xx, h_xx, N_x);
    transform_kernel<32, true><<<TGRID, BLK, 0, stream>>>(c, W_cx, b_cx, h_cx, N_c);
    transform_kernel<48, true><<<TGRID, BLK, 0, stream>>>(r, W_rx, b_rx, h_rx, N_r);
    transform_kernel<32, true><<<TGRID, BLK, 0, stream>>>(c, W_c,  b_c,  out_c, N_c);
    transform_kernel<48, true><<<TGRID, BLK, 0, stream>>>(r, W_r,  b_r,  out_r, N_r);

    // combined CSR over all 3 relations
    hipMemsetAsync(deg, 0, (size_t)N_x * sizeof(int), stream);
    hist3_kernel<<<EGRID, BLK, 0, stream>>>(exx_d, E_xx, ecx_d, E_cx, erx_d, E_rx, deg);
    scan_partial_kernel  <<<SCAN_BLOCKS, 256, 0, stream>>>(deg, N_x, bsum);
    scan_blocksums_kernel<<<1, SCAN_BLOCKS, 0, stream>>>(bsum, bbase, offsets, N_x);
    scan_write_kernel    <<<SCAN_BLOCKS, 256, 0, stream>>>(deg, offsets, bbase, N_x);
    bucket3_kernel<<<EGRID, BLK, 0, stream>>>(
        exx_s, exx_d, E_xx, 0,
        ecx_s, ecx_d, E_cx, N_x,
        erx_s, erx_d, E_rx, N_x + N_c,
        offsets, deg, rows);

    // fused gather + pool (writes out_x directly; no agg writeback, no 4th pass)
    gather_pool_kernel<<<2048, BLK, 0, stream>>>(offsets, rows, H, agg,
                                                 W_pool, b_pool, out_x, N_x);
}